// Round 1
// baseline (460.831 us; speedup 1.0000x reference)
//
#include <hip/hip_runtime.h>

// Problem dims
#define LL 1024
#define BB 8
#define EE 1024
#define HH 16
#define HD 64
#define MROWS (LL*BB)   // 8192 token rows

typedef __attribute__((ext_vector_type(8))) short short8v;  // 8 bf16 (4 VGPRs)
typedef __attribute__((ext_vector_type(4))) float f32x4;

__device__ __forceinline__ unsigned short tobf(float f) {
    union { float f; unsigned u; } un; un.f = f;
    unsigned u = un.u;
    u += 0x7fffu + ((u >> 16) & 1u);   // round-to-nearest-even
    return (unsigned short)(u >> 16);
}

// ---------------- weight f32 -> bf16 (E*E = 2^20 elems, grid covers exactly) ---
__global__ __launch_bounds__(256) void convw_kernel(const float* __restrict__ w,
                                                    unsigned short* __restrict__ o) {
    int i = (blockIdx.x * 256 + threadIdx.x) * 4;
    float4 v = *(const float4*)&w[i];
    ushort4 r;
    r.x = tobf(v.x); r.y = tobf(v.y); r.z = tobf(v.z); r.w = tobf(v.w);
    *(ushort4*)&o[i] = r;
}

// ---------------- LayerNorm: one block per token row, E=1024, 256 thr ---------
__global__ __launch_bounds__(256) void ln_kernel(const float* __restrict__ x,
                                                 const float* __restrict__ gamma,
                                                 const float* __restrict__ beta,
                                                 unsigned short* __restrict__ out) {
    const int row = blockIdx.x;
    const int tid = threadIdx.x;
    const float4 v = *(const float4*)&x[(size_t)row * EE + tid * 4];
    float s = v.x + v.y + v.z + v.w;
    float q = v.x*v.x + v.y*v.y + v.z*v.z + v.w*v.w;
    #pragma unroll
    for (int off = 1; off < 64; off <<= 1) {
        s += __shfl_xor(s, off);
        q += __shfl_xor(q, off);
    }
    __shared__ float ss[4], sq[4];
    const int wv = tid >> 6;
    if ((tid & 63) == 0) { ss[wv] = s; sq[wv] = q; }
    __syncthreads();
    s = ss[0] + ss[1] + ss[2] + ss[3];
    q = sq[0] + sq[1] + sq[2] + sq[3];
    const float mu = s * (1.0f / EE);
    const float var = q * (1.0f / EE) - mu * mu;
    const float rs = rsqrtf(var + 1e-5f);
    ushort4 o;
    o.x = tobf((v.x - mu) * rs * gamma[tid*4+0] + beta[tid*4+0]);
    o.y = tobf((v.y - mu) * rs * gamma[tid*4+1] + beta[tid*4+1]);
    o.z = tobf((v.z - mu) * rs * gamma[tid*4+2] + beta[tid*4+2]);
    o.w = tobf((v.w - mu) * rs * gamma[tid*4+3] + beta[tid*4+3]);
    *(ushort4*)&out[(size_t)row * EE + tid * 4] = o;
}

// ---------------- GEMM: C = A(bf16 M x K rowmajor) @ W^T(bf16 N x K rowmajor) --
// 64x64 tile, BK=32, 4 waves each 32x32 (2x2 frags of 16x16x32 MFMA).
// EPI: 0=Q (bias, *SCALE, scatter (B,H,L,HD)), 1=K (scatter (B,H,L,HD)),
//      2=V (scatter transposed (B,H,HD,L)), 3=O (bias + residual, f32 out)
template<int EPI>
__global__ __launch_bounds__(256) void gemm_bt(const unsigned short* __restrict__ A,
                                               const unsigned short* __restrict__ W,
                                               const float* __restrict__ bias,
                                               const float* __restrict__ xres,
                                               unsigned short* __restrict__ outb,
                                               float* __restrict__ outf) {
    __shared__ __attribute__((aligned(16))) unsigned short a_sh[64][40]; // +8 pad: bank-spread
    __shared__ __attribute__((aligned(16))) unsigned short b_sh[64][40];
    const int tid  = threadIdx.x;
    const int lane = tid & 63;
    const int wave = tid >> 6;
    const int bm = blockIdx.y * 64;
    const int bn = blockIdx.x * 64;
    const int wr = (wave >> 1) * 32;
    const int wc = (wave & 1) * 32;
    const int l16 = lane & 15;
    const int lk  = (lane >> 4) * 8;
    const int srow = tid >> 2;
    const int scol = (tid & 3) * 8;
    f32x4 acc[2][2] = {};
    for (int k0 = 0; k0 < EE; k0 += 32) {
        *(uint4*)&a_sh[srow][scol] = *(const uint4*)&A[(size_t)(bm + srow) * EE + k0 + scol];
        *(uint4*)&b_sh[srow][scol] = *(const uint4*)&W[(size_t)(bn + srow) * EE + k0 + scol];
        __syncthreads();
        short8v af[2], bf[2];
        #pragma unroll
        for (int mi = 0; mi < 2; ++mi) af[mi] = *(const short8v*)&a_sh[wr + mi*16 + l16][lk];
        #pragma unroll
        for (int ni = 0; ni < 2; ++ni) bf[ni] = *(const short8v*)&b_sh[wc + ni*16 + l16][lk];
        #pragma unroll
        for (int mi = 0; mi < 2; ++mi)
            #pragma unroll
            for (int ni = 0; ni < 2; ++ni)
                acc[mi][ni] = __builtin_amdgcn_mfma_f32_16x16x32_bf16(af[mi], bf[ni], acc[mi][ni], 0, 0, 0);
        __syncthreads();
    }
    #pragma unroll
    for (int mi = 0; mi < 2; ++mi) {
        #pragma unroll
        for (int ni = 0; ni < 2; ++ni) {
            #pragma unroll
            for (int r = 0; r < 4; ++r) {
                const int m = bm + wr + mi*16 + (lane >> 4) * 4 + r;
                const int n = bn + wc + ni*16 + l16;
                float v = acc[mi][ni][r];
                if constexpr (EPI == 0) {
                    v = (v + bias[n]) * 0.125f;  // SCALE = HD^-0.5
                    const int l = m >> 3, b = m & 7, h = n >> 6, d = n & 63;
                    outb[((size_t)(b*HH + h) * LL + l) * HD + d] = tobf(v);
                } else if constexpr (EPI == 1) {
                    v = v + bias[n];
                    const int l = m >> 3, b = m & 7, h = n >> 6, d = n & 63;
                    outb[((size_t)(b*HH + h) * LL + l) * HD + d] = tobf(v);
                } else if constexpr (EPI == 2) {
                    v = v + bias[n];
                    const int l = m >> 3, b = m & 7, h = n >> 6, d = n & 63;
                    outb[((size_t)(b*HH + h) * HD + d) * LL + l] = tobf(v);  // V transposed
                } else {
                    outf[(size_t)m * EE + n] = v + bias[n] + xres[(size_t)m * EE + n];
                }
            }
        }
    }
}

// ---------------- Flash attention: 1 wave per (b*h, 16-row q tile) ------------
// Per iter: 32 keys. S = Q K^T (C-layout rows=q), online softmax with 16-lane
// shfl reductions, P -> LDS -> A-frag, PV with V^T giving contiguous B-frags.
__global__ __launch_bounds__(64) void attn_kernel(const unsigned short* __restrict__ qarr,
                                                  const unsigned short* __restrict__ karr,
                                                  const unsigned short* __restrict__ vtarr,
                                                  const float* __restrict__ mask,
                                                  unsigned short* __restrict__ attn_out) {
    const int qt = blockIdx.x;          // q tile (16 rows)
    const int bh = blockIdx.y;          // b*HH + h
    const int lane = threadIdx.x;
    const int l16 = lane & 15;
    const int lg  = lane >> 4;          // 16-lane group id, rows lg*4..lg*4+3
    const int lk  = lg * 8;
    const unsigned short* qb = qarr + (size_t)bh * LL * HD;
    const unsigned short* kb = karr + (size_t)bh * LL * HD;
    const unsigned short* vb = vtarr + (size_t)bh * HD * LL;

    short8v aq[2];
    #pragma unroll
    for (int c = 0; c < 2; ++c)
        aq[c] = *(const short8v*)&qb[(size_t)(qt*16 + l16) * HD + c*32 + lk];

    f32x4 acc[4] = {};
    float mrun[4], srun[4];
    #pragma unroll
    for (int r = 0; r < 4; ++r) { mrun[r] = -1e30f; srun[r] = 0.f; }

    __shared__ __attribute__((aligned(16))) unsigned short p_sh[16][40];
    const int qrow0 = qt*16 + lg*4;

    for (int kv = 0; kv < LL; kv += 32) {
        f32x4 s0 = {}, s1 = {};
        #pragma unroll
        for (int c = 0; c < 2; ++c) {
            short8v bk0 = *(const short8v*)&kb[(size_t)(kv      + l16) * HD + c*32 + lk];
            short8v bk1 = *(const short8v*)&kb[(size_t)(kv + 16 + l16) * HD + c*32 + lk];
            s0 = __builtin_amdgcn_mfma_f32_16x16x32_bf16(aq[c], bk0, s0, 0, 0, 0);
            s1 = __builtin_amdgcn_mfma_f32_16x16x32_bf16(aq[c], bk1, s1, 0, 0, 0);
        }
        float al[4];
        #pragma unroll
        for (int r = 0; r < 4; ++r) {
            s0[r] += mask[(size_t)(qrow0 + r) * LL + kv + l16];
            s1[r] += mask[(size_t)(qrow0 + r) * LL + kv + 16 + l16];
            float pm = fmaxf(s0[r], s1[r]);
            #pragma unroll
            for (int off = 1; off < 16; off <<= 1) pm = fmaxf(pm, __shfl_xor(pm, off));
            const float mn = fmaxf(mrun[r], pm);
            al[r] = __expf(mrun[r] - mn);
            mrun[r] = mn;
            s0[r] = __expf(s0[r] - mn);
            s1[r] = __expf(s1[r] - mn);
            float rs = s0[r] + s1[r];
            #pragma unroll
            for (int off = 1; off < 16; off <<= 1) rs += __shfl_xor(rs, off);
            srun[r] = srun[r] * al[r] + rs;
        }
        #pragma unroll
        for (int n = 0; n < 4; ++n)
            #pragma unroll
            for (int r = 0; r < 4; ++r) acc[n][r] *= al[r];
        // P (C-layout) -> LDS -> A-frag layout
        #pragma unroll
        for (int r = 0; r < 4; ++r) {
            p_sh[lg*4 + r][l16]      = tobf(s0[r]);
            p_sh[lg*4 + r][16 + l16] = tobf(s1[r]);
        }
        __syncthreads();
        const short8v pa = *(const short8v*)&p_sh[l16][lk];
        #pragma unroll
        for (int n = 0; n < 4; ++n) {
            short8v bv = *(const short8v*)&vb[(size_t)(n*16 + l16) * LL + kv + lk];
            acc[n] = __builtin_amdgcn_mfma_f32_16x16x32_bf16(pa, bv, acc[n], 0, 0, 0);
        }
        __syncthreads();
    }
    const int b = bh >> 4, h = bh & 15;
    #pragma unroll
    for (int n = 0; n < 4; ++n)
        #pragma unroll
        for (int r = 0; r < 4; ++r) {
            const int ltok = qrow0 + r;
            const float ov = acc[n][r] / srun[r];
            attn_out[((size_t)ltok * BB + b) * EE + h*HD + n*16 + l16] = tobf(ov);
        }
}

extern "C" void kernel_launch(void* const* d_in, const int* in_sizes, int n_in,
                              void* d_out, int out_size, void* d_ws, size_t ws_size,
                              hipStream_t stream) {
    (void)in_sizes; (void)n_in; (void)out_size; (void)ws_size;
    const float* x     = (const float*)d_in[0];
    const float* mask  = (const float*)d_in[1];
    const float* Wq    = (const float*)d_in[2];
    const float* bq    = (const float*)d_in[3];
    const float* Wk    = (const float*)d_in[4];
    const float* bk    = (const float*)d_in[5];
    const float* Wv    = (const float*)d_in[6];
    const float* bv    = (const float*)d_in[7];
    const float* Wo    = (const float*)d_in[8];
    const float* bo    = (const float*)d_in[9];
    const float* gamma = (const float*)d_in[10];
    const float* beta  = (const float*)d_in[11];
    float* out = (float*)d_out;

    // workspace layout (ushort units); total = 75,497,472 bytes
    unsigned short* ws = (unsigned short*)d_ws;
    unsigned short* ln  = ws;                         // 8192*1024        (also reused as attn_out)
    unsigned short* wqb = ln  + (size_t)MROWS * EE;   // 1M
    unsigned short* wkb = wqb + (size_t)EE * EE;
    unsigned short* wvb = wkb + (size_t)EE * EE;
    unsigned short* wob = wvb + (size_t)EE * EE;
    unsigned short* qb  = wob + (size_t)EE * EE;      // (B,H,L,HD)
    unsigned short* kbp = qb  + (size_t)BB * HH * LL * HD;
    unsigned short* vtb = kbp + (size_t)BB * HH * LL * HD;  // (B,H,HD,L)
    unsigned short* attnb = ln;                       // reuse: ln dead after QKV GEMMs

    convw_kernel<<<1024, 256, 0, stream>>>(Wq, wqb);
    convw_kernel<<<1024, 256, 0, stream>>>(Wk, wkb);
    convw_kernel<<<1024, 256, 0, stream>>>(Wv, wvb);
    convw_kernel<<<1024, 256, 0, stream>>>(Wo, wob);
    ln_kernel<<<MROWS, 256, 0, stream>>>(x, gamma, beta, ln);

    dim3 ggrid(EE / 64, MROWS / 64);  // (16, 128)
    gemm_bt<0><<<ggrid, 256, 0, stream>>>(ln, wqb, bq, nullptr, qb,  nullptr);
    gemm_bt<1><<<ggrid, 256, 0, stream>>>(ln, wkb, bk, nullptr, kbp, nullptr);
    gemm_bt<2><<<ggrid, 256, 0, stream>>>(ln, wvb, bv, nullptr, vtb, nullptr);

    attn_kernel<<<dim3(LL / 16, BB * HH), 64, 0, stream>>>(qb, kbp, vtb, mask, attnb);

    gemm_bt<3><<<ggrid, 256, 0, stream>>>(attnb, wob, bo, x, nullptr, out);
}

// Round 2
// 394.054 us; speedup vs baseline: 1.1695x; 1.1695x over previous
//
#include <hip/hip_runtime.h>

// Problem dims
#define LL 1024
#define BB 8
#define EE 1024
#define HH 16
#define HD 64
#define MROWS (LL*BB)   // 8192 token rows

typedef __attribute__((ext_vector_type(8))) short short8v;  // 8 bf16 (4 VGPRs)
typedef __attribute__((ext_vector_type(4))) float f32x4;

__device__ __forceinline__ unsigned short tobf(float f) {
    union { float f; unsigned u; } un; un.f = f;
    unsigned u = un.u;
    u += 0x7fffu + ((u >> 16) & 1u);   // round-to-nearest-even
    return (unsigned short)(u >> 16);
}

__device__ __forceinline__ void load_lds16(const unsigned short* g, unsigned short* l) {
    // async global->LDS, 16B per lane; LDS dest = wave-uniform base + lane*16
    __builtin_amdgcn_global_load_lds((const __attribute__((address_space(1))) unsigned int*)g,
                                     (__attribute__((address_space(3))) unsigned int*)l,
                                     16, 0, 0);
}

// ---------------- weight f32 -> bf16, 4 weights in one launch -----------------
__global__ __launch_bounds__(256) void convw4_kernel(const float* __restrict__ w0,
                                                     const float* __restrict__ w1,
                                                     const float* __restrict__ w2,
                                                     const float* __restrict__ w3,
                                                     unsigned short* __restrict__ o0,
                                                     unsigned short* __restrict__ o1,
                                                     unsigned short* __restrict__ o2,
                                                     unsigned short* __restrict__ o3) {
    const float* w; unsigned short* o;
    switch (blockIdx.y) {
        case 0:  w = w0; o = o0; break;
        case 1:  w = w1; o = o1; break;
        case 2:  w = w2; o = o2; break;
        default: w = w3; o = o3; break;
    }
    int i = (blockIdx.x * 256 + threadIdx.x) * 4;
    float4 v = *(const float4*)&w[i];
    ushort4 r;
    r.x = tobf(v.x); r.y = tobf(v.y); r.z = tobf(v.z); r.w = tobf(v.w);
    *(ushort4*)&o[i] = r;
}

// ---------------- LayerNorm: one block per token row, E=1024, 256 thr ---------
__global__ __launch_bounds__(256) void ln_kernel(const float* __restrict__ x,
                                                 const float* __restrict__ gamma,
                                                 const float* __restrict__ beta,
                                                 unsigned short* __restrict__ out) {
    const int row = blockIdx.x;
    const int tid = threadIdx.x;
    const float4 v = *(const float4*)&x[(size_t)row * EE + tid * 4];
    float s = v.x + v.y + v.z + v.w;
    float q = v.x*v.x + v.y*v.y + v.z*v.z + v.w*v.w;
    #pragma unroll
    for (int off = 1; off < 64; off <<= 1) {
        s += __shfl_xor(s, off);
        q += __shfl_xor(q, off);
    }
    __shared__ float ss[4], sq[4];
    const int wv = tid >> 6;
    if ((tid & 63) == 0) { ss[wv] = s; sq[wv] = q; }
    __syncthreads();
    s = ss[0] + ss[1] + ss[2] + ss[3];
    q = sq[0] + sq[1] + sq[2] + sq[3];
    const float mu = s * (1.0f / EE);
    const float var = q * (1.0f / EE) - mu * mu;
    const float rs = rsqrtf(var + 1e-5f);
    ushort4 o;
    o.x = tobf((v.x - mu) * rs * gamma[tid*4+0] + beta[tid*4+0]);
    o.y = tobf((v.y - mu) * rs * gamma[tid*4+1] + beta[tid*4+1]);
    o.z = tobf((v.z - mu) * rs * gamma[tid*4+2] + beta[tid*4+2]);
    o.w = tobf((v.w - mu) * rs * gamma[tid*4+3] + beta[tid*4+3]);
    *(ushort4*)&out[(size_t)row * EE + tid * 4] = o;
}

// ---------------- 128x128-tile GEMM core (m97 structure) ----------------------
// C = A(M x 1024 rowmajor bf16) @ W^T (W: N x 1024 rowmajor bf16)
// 256 thr = 4 waves; wave computes 64x64 via 4x4 frags of 16x16x32 MFMA.
// Staging: global_load_lds width 16 into linear LDS [128][32].
#define GEMM128_BODY(A_, W_)                                                              \
    __shared__ unsigned short a_sh[128*32];                                               \
    __shared__ unsigned short b_sh[128*32];                                               \
    const int tid = threadIdx.x, lane = tid & 63, wave = tid >> 6;                        \
    const int bm = blockIdx.y * 128, bn = blockIdx.x * 128;                               \
    const int wr = (wave >> 1) * 64, wc = (wave & 1) * 64;                                \
    const int l16 = lane & 15, lk8 = (lane >> 4) * 8;                                     \
    const int grow = lane >> 2, gcol = (lane & 3) * 8;                                    \
    f32x4 acc[4][4] = {};                                                                 \
    for (int k0 = 0; k0 < EE; k0 += 32) {                                                 \
        _Pragma("unroll")                                                                 \
        for (int i = 0; i < 2; ++i) {                                                     \
            const int c = wave * 2 + i;                                                   \
            load_lds16(&A_[(size_t)(bm + c*16 + grow)*EE + k0 + gcol], a_sh + c*512);     \
            load_lds16(&W_[(size_t)(bn + c*16 + grow)*EE + k0 + gcol], b_sh + c*512);     \
        }                                                                                 \
        __syncthreads();                                                                  \
        short8v af[4], bf[4];                                                             \
        _Pragma("unroll")                                                                 \
        for (int mi = 0; mi < 4; ++mi) af[mi] = *(const short8v*)&a_sh[(wr + mi*16 + l16)*32 + lk8]; \
        _Pragma("unroll")                                                                 \
        for (int ni = 0; ni < 4; ++ni) bf[ni] = *(const short8v*)&b_sh[(wc + ni*16 + l16)*32 + lk8]; \
        _Pragma("unroll")                                                                 \
        for (int mi = 0; mi < 4; ++mi)                                                    \
            _Pragma("unroll")                                                             \
            for (int ni = 0; ni < 4; ++ni)                                                \
                acc[mi][ni] = __builtin_amdgcn_mfma_f32_16x16x32_bf16(af[mi], bf[ni], acc[mi][ni], 0, 0, 0); \
        __syncthreads();                                                                  \
    }

// QKV fused: W = [Wq;Wk;Wv] (3072 x 1024). Segment uniform per block (BN=128 | 1024).
__global__ __launch_bounds__(256) void gemm_qkv(const unsigned short* __restrict__ A,
                                                const unsigned short* __restrict__ W,
                                                const float* __restrict__ bq,
                                                const float* __restrict__ bk,
                                                const float* __restrict__ bv,
                                                unsigned short* __restrict__ qo,
                                                unsigned short* __restrict__ ko,
                                                unsigned short* __restrict__ vo) {
    GEMM128_BODY(A, W)
    const int seg = blockIdx.x >> 3;
    const float* bias = seg == 0 ? bq : (seg == 1 ? bk : bv);
    #pragma unroll
    for (int mi = 0; mi < 4; ++mi) {
        #pragma unroll
        for (int ni = 0; ni < 4; ++ni) {
            #pragma unroll
            for (int r = 0; r < 4; ++r) {
                const int m  = bm + wr + mi*16 + (lane >> 4)*4 + r;
                const int nn = (bn & 1023) + wc + ni*16 + l16;
                const float v = acc[mi][ni][r] + bias[nn];
                const int l = m >> 3, b = m & 7, h = nn >> 6, d = nn & 63;
                if (seg == 0)      qo[((size_t)(b*HH + h) * LL + l) * HD + d] = tobf(v * 0.125f);
                else if (seg == 1) ko[((size_t)(b*HH + h) * LL + l) * HD + d] = tobf(v);
                else               vo[((size_t)(b*HH + h) * HD + d) * LL + l] = tobf(v); // V^T
            }
        }
    }
}

// Output projection + bias + residual, f32 out.
__global__ __launch_bounds__(256) void gemm_o(const unsigned short* __restrict__ A,
                                              const unsigned short* __restrict__ W,
                                              const float* __restrict__ bias,
                                              const float* __restrict__ xres,
                                              float* __restrict__ outf) {
    GEMM128_BODY(A, W)
    #pragma unroll
    for (int mi = 0; mi < 4; ++mi) {
        #pragma unroll
        for (int ni = 0; ni < 4; ++ni) {
            #pragma unroll
            for (int r = 0; r < 4; ++r) {
                const int m = bm + wr + mi*16 + (lane >> 4)*4 + r;
                const int n = bn + wc + ni*16 + l16;
                outf[(size_t)m * EE + n] = acc[mi][ni][r] + bias[n] + xres[(size_t)m * EE + n];
            }
        }
    }
}

// ---------------- Flash attention: 4 waves/block, 32 q-rows/wave, 64-key steps -
// K-tile and V^T-tile staged in padded LDS shared by all waves; P is wave-private
// in LDS (no barrier on the P round-trip).
__global__ __launch_bounds__(256) void attn_kernel(const unsigned short* __restrict__ qarr,
                                                   const unsigned short* __restrict__ karr,
                                                   const unsigned short* __restrict__ vtarr,
                                                   const float* __restrict__ mask,
                                                   unsigned short* __restrict__ attn_out) {
    __shared__ __attribute__((aligned(16))) unsigned short k_sh[64][72];   // keys x d, +8 pad
    __shared__ __attribute__((aligned(16))) unsigned short vt_sh[64][72];  // d x keys, +8 pad
    __shared__ __attribute__((aligned(16))) unsigned short p_sh[4][32][72];
    const int tid = threadIdx.x, lane = tid & 63, wave = tid >> 6;
    const int l16 = lane & 15, lg = lane >> 4, lk = lg * 8;
    const int bh = blockIdx.y;
    const int q0 = blockIdx.x * 128 + wave * 32;
    const unsigned short* qb = qarr  + (size_t)bh * LL * HD;
    const unsigned short* kb = karr  + (size_t)bh * LL * HD;
    const unsigned short* vb = vtarr + (size_t)bh * HD * LL;

    short8v aq[2][2];
    #pragma unroll
    for (int mi = 0; mi < 2; ++mi)
        #pragma unroll
        for (int c = 0; c < 2; ++c)
            aq[mi][c] = *(const short8v*)&qb[(size_t)(q0 + mi*16 + l16)*HD + c*32 + lk];

    f32x4 acc[2][4] = {};
    float mrun[2][4], srun[2][4];
    #pragma unroll
    for (int mi = 0; mi < 2; ++mi)
        #pragma unroll
        for (int r = 0; r < 4; ++r) { mrun[mi][r] = -1e30f; srun[mi][r] = 0.f; }

    const int str = tid >> 3;          // stage row 0..31 (and +32)
    const int stc = (tid & 7) * 8;     // stage col

    for (int kv = 0; kv < LL; kv += 64) {
        // issue global loads early (reg staging; LDS writes after barrier)
        const uint4 kreg0 = *(const uint4*)&kb[(size_t)(kv + str) * HD + stc];
        const uint4 kreg1 = *(const uint4*)&kb[(size_t)(kv + str + 32) * HD + stc];
        const uint4 vreg0 = *(const uint4*)&vb[(size_t)str * LL + kv + stc];
        const uint4 vreg1 = *(const uint4*)&vb[(size_t)(str + 32) * LL + kv + stc];
        __syncthreads();   // all waves done reading previous tiles
        *(uint4*)&k_sh[str][stc]       = kreg0;
        *(uint4*)&k_sh[str + 32][stc]  = kreg1;
        *(uint4*)&vt_sh[str][stc]      = vreg0;
        *(uint4*)&vt_sh[str + 32][stc] = vreg1;
        __syncthreads();   // tiles visible

        // S = Q K^T  (16 MFMA per wave)
        f32x4 s[2][4] = {};
        #pragma unroll
        for (int c = 0; c < 2; ++c) {
            short8v bk[4];
            #pragma unroll
            for (int ni = 0; ni < 4; ++ni)
                bk[ni] = *(const short8v*)&k_sh[ni*16 + l16][c*32 + lk];
            #pragma unroll
            for (int mi = 0; mi < 2; ++mi)
                #pragma unroll
                for (int ni = 0; ni < 4; ++ni)
                    s[mi][ni] = __builtin_amdgcn_mfma_f32_16x16x32_bf16(aq[mi][c], bk[ni], s[mi][ni], 0, 0, 0);
        }
        // mask + online softmax over 64 columns
        #pragma unroll
        for (int mi = 0; mi < 2; ++mi) {
            #pragma unroll
            for (int r = 0; r < 4; ++r) {
                const int qrow = q0 + mi*16 + lg*4 + r;
                const float* mrow = &mask[(size_t)qrow * LL + kv];
                #pragma unroll
                for (int ni = 0; ni < 4; ++ni) s[mi][ni][r] += mrow[ni*16 + l16];
                float pm = fmaxf(fmaxf(s[mi][0][r], s[mi][1][r]), fmaxf(s[mi][2][r], s[mi][3][r]));
                #pragma unroll
                for (int off = 1; off < 16; off <<= 1) pm = fmaxf(pm, __shfl_xor(pm, off));
                const float mn = fmaxf(mrun[mi][r], pm);
                const float al = __expf(mrun[mi][r] - mn);
                mrun[mi][r] = mn;
                float rs = 0.f;
                #pragma unroll
                for (int ni = 0; ni < 4; ++ni) {
                    s[mi][ni][r] = __expf(s[mi][ni][r] - mn);
                    rs += s[mi][ni][r];
                }
                #pragma unroll
                for (int off = 1; off < 16; off <<= 1) rs += __shfl_xor(rs, off);
                srun[mi][r] = srun[mi][r] * al + rs;
                #pragma unroll
                for (int n = 0; n < 4; ++n) acc[mi][n][r] *= al;
                #pragma unroll
                for (int ni = 0; ni < 4; ++ni)
                    p_sh[wave][mi*16 + lg*4 + r][ni*16 + l16] = tobf(s[mi][ni][r]);
            }
        }
        // O += P V   (16 MFMA per wave; p_sh wave-private -> no barrier)
        #pragma unroll
        for (int mi = 0; mi < 2; ++mi) {
            short8v pa[2];
            #pragma unroll
            for (int kk = 0; kk < 2; ++kk)
                pa[kk] = *(const short8v*)&p_sh[wave][mi*16 + l16][kk*32 + lk];
            #pragma unroll
            for (int n = 0; n < 4; ++n) {
                #pragma unroll
                for (int kk = 0; kk < 2; ++kk) {
                    const short8v bvf = *(const short8v*)&vt_sh[n*16 + l16][kk*32 + lk];
                    acc[mi][n] = __builtin_amdgcn_mfma_f32_16x16x32_bf16(pa[kk], bvf, acc[mi][n], 0, 0, 0);
                }
            }
        }
    }
    const int b = bh >> 4, h = bh & 15;
    #pragma unroll
    for (int mi = 0; mi < 2; ++mi) {
        #pragma unroll
        for (int r = 0; r < 4; ++r) {
            const float inv = 1.0f / srun[mi][r];
            const int ltok = q0 + mi*16 + lg*4 + r;
            #pragma unroll
            for (int n = 0; n < 4; ++n)
                attn_out[((size_t)ltok * BB + b) * EE + h*HD + n*16 + l16] = tobf(acc[mi][n][r] * inv);
        }
    }
}

extern "C" void kernel_launch(void* const* d_in, const int* in_sizes, int n_in,
                              void* d_out, int out_size, void* d_ws, size_t ws_size,
                              hipStream_t stream) {
    (void)in_sizes; (void)n_in; (void)out_size; (void)ws_size;
    const float* x     = (const float*)d_in[0];
    const float* mask  = (const float*)d_in[1];
    const float* Wq    = (const float*)d_in[2];
    const float* bq    = (const float*)d_in[3];
    const float* Wk    = (const float*)d_in[4];
    const float* bk    = (const float*)d_in[5];
    const float* Wv    = (const float*)d_in[6];
    const float* bv    = (const float*)d_in[7];
    const float* Wo    = (const float*)d_in[8];
    const float* bo    = (const float*)d_in[9];
    const float* gamma = (const float*)d_in[10];
    const float* beta  = (const float*)d_in[11];
    float* out = (float*)d_out;

    // workspace layout (ushort units); total = 72 MB
    unsigned short* ws   = (unsigned short*)d_ws;
    unsigned short* ln   = ws;                          // 8192*1024 (reused as attnb)
    unsigned short* wqkv = ln   + (size_t)MROWS * EE;   // 3 x 1024 x 1024 (Wq;Wk;Wv)
    unsigned short* wob  = wqkv + (size_t)3 * EE * EE;
    unsigned short* qb   = wob  + (size_t)EE * EE;      // (B,H,L,HD)
    unsigned short* kbp  = qb   + (size_t)BB * HH * LL * HD;
    unsigned short* vtb  = kbp  + (size_t)BB * HH * LL * HD;  // (B,H,HD,L)
    unsigned short* attnb = ln;                         // reuse after QKV GEMM

    convw4_kernel<<<dim3(1024, 4), 256, 0, stream>>>(
        Wq, Wk, Wv, Wo,
        wqkv, wqkv + (size_t)EE * EE, wqkv + (size_t)2 * EE * EE, wob);
    ln_kernel<<<MROWS, 256, 0, stream>>>(x, gamma, beta, ln);

    gemm_qkv<<<dim3(24, 64), 256, 0, stream>>>(ln, wqkv, bq, bk, bv, qb, kbp, vtb);

    attn_kernel<<<dim3(LL / 128, BB * HH), 256, 0, stream>>>(qb, kbp, vtb, mask, attnb);

    gemm_o<<<dim3(8, 64), 256, 0, stream>>>(attnb, wob, bo, x, out);
}

// Round 3
// 232.762 us; speedup vs baseline: 1.9798x; 1.6929x over previous
//
#include <hip/hip_runtime.h>

// Problem dims
#define LL 1024
#define BB 8
#define EE 1024
#define HH 16
#define HD 64
#define MROWS (LL*BB)   // 8192 token rows

typedef __attribute__((ext_vector_type(8))) short short8v;   // 8 bf16 (4 VGPRs)
typedef __attribute__((ext_vector_type(4))) float f32x4;
typedef __attribute__((ext_vector_type(16))) float f32x16;

__device__ __forceinline__ unsigned short tobf(float f) {
    union { float f; unsigned u; } un; un.f = f;
    unsigned u = un.u;
    u += 0x7fffu + ((u >> 16) & 1u);   // round-to-nearest-even
    return (unsigned short)(u >> 16);
}

__device__ __forceinline__ void load_lds16(const unsigned short* g, unsigned short* l) {
    // async global->LDS, 16B per lane; LDS dest = wave-uniform base + lane*16
    __builtin_amdgcn_global_load_lds((const __attribute__((address_space(1))) unsigned int*)g,
                                     (__attribute__((address_space(3))) unsigned int*)l,
                                     16, 0, 0);
}

// ---------------- weight f32 -> bf16, 4 weights in one launch -----------------
__global__ __launch_bounds__(256) void convw4_kernel(const float* __restrict__ w0,
                                                     const float* __restrict__ w1,
                                                     const float* __restrict__ w2,
                                                     const float* __restrict__ w3,
                                                     unsigned short* __restrict__ o0,
                                                     unsigned short* __restrict__ o1,
                                                     unsigned short* __restrict__ o2,
                                                     unsigned short* __restrict__ o3) {
    const float* w; unsigned short* o;
    switch (blockIdx.y) {
        case 0:  w = w0; o = o0; break;
        case 1:  w = w1; o = o1; break;
        case 2:  w = w2; o = o2; break;
        default: w = w3; o = o3; break;
    }
    int i = (blockIdx.x * 256 + threadIdx.x) * 4;
    float4 v = *(const float4*)&w[i];
    ushort4 r;
    r.x = tobf(v.x); r.y = tobf(v.y); r.z = tobf(v.z); r.w = tobf(v.w);
    *(ushort4*)&o[i] = r;
}

// ---------------- LayerNorm: one block per token row, E=1024, 256 thr ---------
__global__ __launch_bounds__(256) void ln_kernel(const float* __restrict__ x,
                                                 const float* __restrict__ gamma,
                                                 const float* __restrict__ beta,
                                                 unsigned short* __restrict__ out) {
    const int row = blockIdx.x;
    const int tid = threadIdx.x;
    const float4 v = *(const float4*)&x[(size_t)row * EE + tid * 4];
    float s = v.x + v.y + v.z + v.w;
    float q = v.x*v.x + v.y*v.y + v.z*v.z + v.w*v.w;
    #pragma unroll
    for (int off = 1; off < 64; off <<= 1) {
        s += __shfl_xor(s, off);
        q += __shfl_xor(q, off);
    }
    __shared__ float ss[4], sq[4];
    const int wv = tid >> 6;
    if ((tid & 63) == 0) { ss[wv] = s; sq[wv] = q; }
    __syncthreads();
    s = ss[0] + ss[1] + ss[2] + ss[3];
    q = sq[0] + sq[1] + sq[2] + sq[3];
    const float mu = s * (1.0f / EE);
    const float var = q * (1.0f / EE) - mu * mu;
    const float rs = rsqrtf(var + 1e-5f);
    ushort4 o;
    o.x = tobf((v.x - mu) * rs * gamma[tid*4+0] + beta[tid*4+0]);
    o.y = tobf((v.y - mu) * rs * gamma[tid*4+1] + beta[tid*4+1]);
    o.z = tobf((v.z - mu) * rs * gamma[tid*4+2] + beta[tid*4+2]);
    o.w = tobf((v.w - mu) * rs * gamma[tid*4+3] + beta[tid*4+3]);
    *(ushort4*)&out[(size_t)row * EE + tid * 4] = o;
}

// ---------------- 128x128-tile GEMM core (m97 structure) ----------------------
#define GEMM128_BODY(A_, W_)                                                              \
    __shared__ unsigned short a_sh[128*32];                                               \
    __shared__ unsigned short b_sh[128*32];                                               \
    const int tid = threadIdx.x, lane = tid & 63, wave = tid >> 6;                        \
    const int bm = blockIdx.y * 128, bn = blockIdx.x * 128;                               \
    const int wr = (wave >> 1) * 64, wc = (wave & 1) * 64;                                \
    const int l16 = lane & 15, lk8 = (lane >> 4) * 8;                                     \
    const int grow = lane >> 2, gcol = (lane & 3) * 8;                                    \
    f32x4 acc[4][4] = {};                                                                 \
    for (int k0 = 0; k0 < EE; k0 += 32) {                                                 \
        _Pragma("unroll")                                                                 \
        for (int i = 0; i < 2; ++i) {                                                     \
            const int c = wave * 2 + i;                                                   \
            load_lds16(&A_[(size_t)(bm + c*16 + grow)*EE + k0 + gcol], a_sh + c*512);     \
            load_lds16(&W_[(size_t)(bn + c*16 + grow)*EE + k0 + gcol], b_sh + c*512);     \
        }                                                                                 \
        __syncthreads();                                                                  \
        short8v af[4], bf[4];                                                             \
        _Pragma("unroll")                                                                 \
        for (int mi = 0; mi < 4; ++mi) af[mi] = *(const short8v*)&a_sh[(wr + mi*16 + l16)*32 + lk8]; \
        _Pragma("unroll")                                                                 \
        for (int ni = 0; ni < 4; ++ni) bf[ni] = *(const short8v*)&b_sh[(wc + ni*16 + l16)*32 + lk8]; \
        _Pragma("unroll")                                                                 \
        for (int mi = 0; mi < 4; ++mi)                                                    \
            _Pragma("unroll")                                                             \
            for (int ni = 0; ni < 4; ++ni)                                                \
                acc[mi][ni] = __builtin_amdgcn_mfma_f32_16x16x32_bf16(af[mi], bf[ni], acc[mi][ni], 0, 0, 0); \
        __syncthreads();                                                                  \
    }

// QKV fused: W = [Wq;Wk;Wv] (3072 x 1024). Segment uniform per block.
__global__ __launch_bounds__(256) void gemm_qkv(const unsigned short* __restrict__ A,
                                                const unsigned short* __restrict__ W,
                                                const float* __restrict__ bq,
                                                const float* __restrict__ bk,
                                                const float* __restrict__ bv,
                                                unsigned short* __restrict__ qo,
                                                unsigned short* __restrict__ ko,
                                                unsigned short* __restrict__ vo) {
    GEMM128_BODY(A, W)
    const int seg = blockIdx.x >> 3;
    const float* bias = seg == 0 ? bq : (seg == 1 ? bk : bv);
    #pragma unroll
    for (int mi = 0; mi < 4; ++mi) {
        #pragma unroll
        for (int ni = 0; ni < 4; ++ni) {
            #pragma unroll
            for (int r = 0; r < 4; ++r) {
                const int m  = bm + wr + mi*16 + (lane >> 4)*4 + r;
                const int nn = (bn & 1023) + wc + ni*16 + l16;
                const float v = acc[mi][ni][r] + bias[nn];
                const int l = m >> 3, b = m & 7, h = nn >> 6, d = nn & 63;
                if (seg == 0)      qo[((size_t)(b*HH + h) * LL + l) * HD + d] = tobf(v * 0.125f);
                else if (seg == 1) ko[((size_t)(b*HH + h) * LL + l) * HD + d] = tobf(v);
                else               vo[((size_t)(b*HH + h) * HD + d) * LL + l] = tobf(v); // V^T
            }
        }
    }
}

// Output projection + bias + residual, f32 out.
__global__ __launch_bounds__(256) void gemm_o(const unsigned short* __restrict__ A,
                                              const unsigned short* __restrict__ W,
                                              const float* __restrict__ bias,
                                              const float* __restrict__ xres,
                                              float* __restrict__ outf) {
    GEMM128_BODY(A, W)
    #pragma unroll
    for (int mi = 0; mi < 4; ++mi) {
        #pragma unroll
        for (int ni = 0; ni < 4; ++ni) {
            #pragma unroll
            for (int r = 0; r < 4; ++r) {
                const int m = bm + wr + mi*16 + (lane >> 4)*4 + r;
                const int n = bn + wc + ni*16 + l16;
                outf[(size_t)m * EE + n] = acc[mi][ni][r] + bias[n] + xres[(size_t)m * EE + n];
            }
        }
    }
}

// ---------------- Flash attention, m214 structure ----------------------------
// 4 waves/block, 32 q/wave (q = lane&31), KV tile 64, swapped QK^T with
// mfma_f32_32x32x16_bf16: S^T[k][q], k lane-local -> in-register softmax.
// P -> bf16 B-frag via v_cvt_pk_bf16_f32 + v_permlane32_swap_b32 (T12).
// K & V^T in double-buffered LDS, global_load_lds w/ pre-swizzled source (T2/T14).
__global__ __launch_bounds__(256) void attn_kernel(const unsigned short* __restrict__ qarr,
                                                   const unsigned short* __restrict__ karr,
                                                   const unsigned short* __restrict__ vtarr,
                                                   const float* __restrict__ mask,
                                                   unsigned short* __restrict__ attn_out) {
    __shared__ __attribute__((aligned(16))) unsigned short k_sh[2][64*64];  // [kv64][d64]
    __shared__ __attribute__((aligned(16))) unsigned short v_sh[2][64*64];  // [d64][kv64]
    const int tid = threadIdx.x, lane = tid & 63, wave = tid >> 6;
    const int l32 = lane & 31, hi = lane >> 5;
    const int bh = blockIdx.y;
    const int qtok = blockIdx.x * 128 + wave * 32 + l32;
    const unsigned short* qb = qarr  + (size_t)bh * LL * HD;
    const unsigned short* kb = karr  + (size_t)bh * LL * HD;
    const unsigned short* vb = vtarr + (size_t)bh * HD * LL;

    // Q B-frag: col q=l32, k-rows d = dc*16 + hi*8 + {0..7}
    short8v qf[4];
    #pragma unroll
    for (int dc = 0; dc < 4; ++dc)
        qf[dc] = *(const short8v*)&qb[(size_t)qtok * HD + dc*16 + hi*8];

    f32x16 acc[2] = {};           // O^T accumulator: dtile 0 (d 0..31), 1 (d 32..63)
    float mrun = -1e30f, srun = 0.f;

    // stage tile (64 keys) via global_load_lds; source chunk pre-swizzled so
    // LDS[row][slot] = global chunk (slot ^ (row&7))  [rule #21 involution]
    auto stage = [&](int buf, int kv) {
        #pragma unroll
        for (int i = 0; i < 2; ++i) {
            const int r = wave*16 + i*8 + (lane >> 3);
            const int c = ((lane & 7) ^ (r & 7)) * 8;
            load_lds16(&kb[(size_t)(kv + r) * HD + c], &k_sh[buf][(wave*16 + i*8) * 64]);
            load_lds16(&vb[(size_t)r * LL + kv + c],   &v_sh[buf][(wave*16 + i*8) * 64]);
        }
    };

    stage(0, 0);
    for (int t = 0; t < LL/64; ++t) {
        const int buf = t & 1;
        __syncthreads();                       // compiler emits vmcnt(0) drain
        if (t < LL/64 - 1) stage(buf ^ 1, (t + 1) * 64);

        #pragma unroll
        for (int sub = 0; sub < 2; ++sub) {
            // ---- S^T = K . Q^T over d=64 (4 chained mfma) ----
            f32x16 s = {};
            #pragma unroll
            for (int dc = 0; dc < 4; ++dc) {
                const int row = sub*32 + l32;
                const short8v kf = *(const short8v*)((const char*)&k_sh[buf][0]
                                     + (size_t)row*128 + (((dc*2 + hi) ^ (l32 & 7)) * 16));
                s = __builtin_amdgcn_mfma_f32_32x32x16_bf16(kf, qf[dc], s, 0, 0, 0);
            }
            // ---- + mask (k contiguous per float4) ----
            const float* mrow = &mask[(size_t)qtok * LL + t*64 + sub*32 + hi*4];
            #pragma unroll
            for (int g = 0; g < 4; ++g) {
                const float4 mv = *(const float4*)&mrow[g*8];
                s[4*g+0] += mv.x; s[4*g+1] += mv.y; s[4*g+2] += mv.z; s[4*g+3] += mv.w;
            }
            // ---- in-register softmax (q column lane-local) ----
            float pm = s[0];
            #pragma unroll
            for (int i = 1; i < 16; ++i) pm = fmaxf(pm, s[i]);
            pm = fmaxf(pm, __shfl_xor(pm, 32));
            if (__any(pm - mrun > 8.0f)) {     // T13 defer-max rescale
                const float mn = fmaxf(mrun, pm);
                const float al = __expf(mrun - mn);
                #pragma unroll
                for (int i = 0; i < 16; ++i) { acc[0][i] *= al; acc[1][i] *= al; }
                srun *= al;
                mrun = mn;
            }
            float p[16]; float rs = 0.f;
            #pragma unroll
            for (int i = 0; i < 16; ++i) { p[i] = __expf(s[i] - mrun); rs += p[i]; }
            rs += __shfl_xor(rs, 32);
            srun += rs;
            // ---- P -> bf16 B-frags via cvt_pk + permlane32_swap (T12) ----
            unsigned w[8];
            #pragma unroll
            for (int j = 0; j < 8; ++j)
                asm("v_cvt_pk_bf16_f32 %0, %1, %2" : "=v"(w[j]) : "v"(p[2*j]), "v"(p[2*j+1]));
            asm volatile("v_permlane32_swap_b32 %0, %1" : "+v"(w[0]), "+v"(w[2]));
            asm volatile("v_permlane32_swap_b32 %0, %1" : "+v"(w[1]), "+v"(w[3]));
            asm volatile("v_permlane32_swap_b32 %0, %1" : "+v"(w[4]), "+v"(w[6]));
            asm volatile("v_permlane32_swap_b32 %0, %1" : "+v"(w[5]), "+v"(w[7]));
            union { uint4 u; short8v s8; } pb0, pb1;
            pb0.u = make_uint4(w[0], w[1], w[2], w[3]);   // k-chain 0..15
            pb1.u = make_uint4(w[4], w[5], w[6], w[7]);   // k-chain 16..31
            // ---- O^T += V^T . P  (4 mfma) ----
            #pragma unroll
            for (int dt = 0; dt < 2; ++dt) {
                const int row = dt*32 + l32;
                const short8v vf0 = *(const short8v*)((const char*)&v_sh[buf][0]
                                      + (size_t)row*128 + ((((sub*2+0)*2 + hi) ^ (l32 & 7)) * 16));
                const short8v vf1 = *(const short8v*)((const char*)&v_sh[buf][0]
                                      + (size_t)row*128 + ((((sub*2+1)*2 + hi) ^ (l32 & 7)) * 16));
                acc[dt] = __builtin_amdgcn_mfma_f32_32x32x16_bf16(vf0, pb0.s8, acc[dt], 0, 0, 0);
                acc[dt] = __builtin_amdgcn_mfma_f32_32x32x16_bf16(vf1, pb1.s8, acc[dt], 0, 0, 0);
            }
        }
    }
    // ---- epilogue: O = acc/srun, packed 8B stores ----
    const float inv = 1.0f / srun;
    const int b = bh >> 4, h = bh & 15;
    unsigned short* orow = attn_out + ((size_t)qtok * BB + b) * EE + h * HD;
    #pragma unroll
    for (int dt = 0; dt < 2; ++dt) {
        #pragma unroll
        for (int g = 0; g < 4; ++g) {
            const float a0 = acc[dt][4*g+0]*inv, a1 = acc[dt][4*g+1]*inv;
            const float a2 = acc[dt][4*g+2]*inv, a3 = acc[dt][4*g+3]*inv;
            unsigned lo, hw;
            asm("v_cvt_pk_bf16_f32 %0, %1, %2" : "=v"(lo) : "v"(a0), "v"(a1));
            asm("v_cvt_pk_bf16_f32 %0, %1, %2" : "=v"(hw) : "v"(a2), "v"(a3));
            *(uint2*)&orow[dt*32 + g*8 + hi*4] = make_uint2(lo, hw);
        }
    }
}

extern "C" void kernel_launch(void* const* d_in, const int* in_sizes, int n_in,
                              void* d_out, int out_size, void* d_ws, size_t ws_size,
                              hipStream_t stream) {
    (void)in_sizes; (void)n_in; (void)out_size; (void)ws_size;
    const float* x     = (const float*)d_in[0];
    const float* mask  = (const float*)d_in[1];
    const float* Wq    = (const float*)d_in[2];
    const float* bq    = (const float*)d_in[3];
    const float* Wk    = (const float*)d_in[4];
    const float* bk    = (const float*)d_in[5];
    const float* Wv    = (const float*)d_in[6];
    const float* bv    = (const float*)d_in[7];
    const float* Wo    = (const float*)d_in[8];
    const float* bo    = (const float*)d_in[9];
    const float* gamma = (const float*)d_in[10];
    const float* beta  = (const float*)d_in[11];
    float* out = (float*)d_out;

    // workspace layout (ushort units)
    unsigned short* ws   = (unsigned short*)d_ws;
    unsigned short* ln   = ws;                          // 8192*1024 (reused as attnb)
    unsigned short* wqkv = ln   + (size_t)MROWS * EE;   // 3 x 1024 x 1024 (Wq;Wk;Wv)
    unsigned short* wob  = wqkv + (size_t)3 * EE * EE;
    unsigned short* qb   = wob  + (size_t)EE * EE;      // (B,H,L,HD)
    unsigned short* kbp  = qb   + (size_t)BB * HH * LL * HD;
    unsigned short* vtb  = kbp  + (size_t)BB * HH * LL * HD;  // (B,H,HD,L)
    unsigned short* attnb = ln;                         // reuse after QKV GEMM

    convw4_kernel<<<dim3(1024, 4), 256, 0, stream>>>(
        Wq, Wk, Wv, Wo,
        wqkv, wqkv + (size_t)EE * EE, wqkv + (size_t)2 * EE * EE, wob);
    ln_kernel<<<MROWS, 256, 0, stream>>>(x, gamma, beta, ln);

    gemm_qkv<<<dim3(24, 64), 256, 0, stream>>>(ln, wqkv, bq, bk, bv, qb, kbp, vtb);

    attn_kernel<<<dim3(LL / 128, BB * HH), 256, 0, stream>>>(qb, kbp, vtb, mask, attnb);

    gemm_o<<<dim3(8, 64), 256, 0, stream>>>(attnb, wob, bo, x, out);
}

// Round 4
// 228.902 us; speedup vs baseline: 2.0132x; 1.0169x over previous
//
#include <hip/hip_runtime.h>

// Problem dims
#define LL 1024
#define BB 8
#define EE 1024
#define HH 16
#define HD 64
#define MROWS (LL*BB)   // 8192 token rows

typedef __attribute__((ext_vector_type(8))) short short8v;   // 8 bf16 (4 VGPRs)
typedef __attribute__((ext_vector_type(4))) float f32x4;
typedef __attribute__((ext_vector_type(16))) float f32x16;

#define LOG2E 1.44269504088896f

__device__ __forceinline__ unsigned short tobf(float f) {
    union { float f; unsigned u; } un; un.f = f;
    unsigned u = un.u;
    u += 0x7fffu + ((u >> 16) & 1u);   // round-to-nearest-even
    return (unsigned short)(u >> 16);
}

__device__ __forceinline__ float max3f(float a, float b, float c) {
    return fmaxf(fmaxf(a, b), c);      // clang fuses to v_max3_f32
}

__device__ __forceinline__ void load_lds16(const unsigned short* g, unsigned short* l) {
    // async global->LDS, 16B per lane; LDS dest = wave-uniform base + lane*16
    __builtin_amdgcn_global_load_lds((const __attribute__((address_space(1))) unsigned int*)g,
                                     (__attribute__((address_space(3))) unsigned int*)l,
                                     16, 0, 0);
}

// ---------------- weight f32 -> bf16, 4 weights in one launch -----------------
__global__ __launch_bounds__(256) void convw4_kernel(const float* __restrict__ w0,
                                                     const float* __restrict__ w1,
                                                     const float* __restrict__ w2,
                                                     const float* __restrict__ w3,
                                                     unsigned short* __restrict__ o0,
                                                     unsigned short* __restrict__ o1,
                                                     unsigned short* __restrict__ o2,
                                                     unsigned short* __restrict__ o3) {
    const float* w; unsigned short* o;
    switch (blockIdx.y) {
        case 0:  w = w0; o = o0; break;
        case 1:  w = w1; o = o1; break;
        case 2:  w = w2; o = o2; break;
        default: w = w3; o = o3; break;
    }
    int i = (blockIdx.x * 256 + threadIdx.x) * 4;
    float4 v = *(const float4*)&w[i];
    ushort4 r;
    r.x = tobf(v.x); r.y = tobf(v.y); r.z = tobf(v.z); r.w = tobf(v.w);
    *(ushort4*)&o[i] = r;
}

// ---------------- LayerNorm: one block per token row, E=1024, 256 thr ---------
__global__ __launch_bounds__(256) void ln_kernel(const float* __restrict__ x,
                                                 const float* __restrict__ gamma,
                                                 const float* __restrict__ beta,
                                                 unsigned short* __restrict__ out) {
    const int row = blockIdx.x;
    const int tid = threadIdx.x;
    const float4 v = *(const float4*)&x[(size_t)row * EE + tid * 4];
    float s = v.x + v.y + v.z + v.w;
    float q = v.x*v.x + v.y*v.y + v.z*v.z + v.w*v.w;
    #pragma unroll
    for (int off = 1; off < 64; off <<= 1) {
        s += __shfl_xor(s, off);
        q += __shfl_xor(q, off);
    }
    __shared__ float ss[4], sq[4];
    const int wv = tid >> 6;
    if ((tid & 63) == 0) { ss[wv] = s; sq[wv] = q; }
    __syncthreads();
    s = ss[0] + ss[1] + ss[2] + ss[3];
    q = sq[0] + sq[1] + sq[2] + sq[3];
    const float mu = s * (1.0f / EE);
    const float var = q * (1.0f / EE) - mu * mu;
    const float rs = rsqrtf(var + 1e-5f);
    ushort4 o;
    o.x = tobf((v.x - mu) * rs * gamma[tid*4+0] + beta[tid*4+0]);
    o.y = tobf((v.y - mu) * rs * gamma[tid*4+1] + beta[tid*4+1]);
    o.z = tobf((v.z - mu) * rs * gamma[tid*4+2] + beta[tid*4+2]);
    o.w = tobf((v.w - mu) * rs * gamma[tid*4+3] + beta[tid*4+3]);
    *(ushort4*)&out[(size_t)row * EE + tid * 4] = o;
}

// ---------------- 128x128-tile GEMM core, BK=64, XOR-swizzled LDS -------------
// C = A(M x 1024 rowmajor bf16) @ W^T (W: N x 1024 rowmajor bf16)
// 256 thr = 4 waves; wave computes 64x64 via 4x4 frags of 16x16x32 MFMA.
// LDS [128][64] linear rows; 16B slot s of row r holds global slot s^(r&7)
// (pre-swizzled global_load_lds source + same XOR on ds_read: rule #21).
#define GEMM128_BODY(A_, W_)                                                              \
    __shared__ unsigned short a_sh[128*64];                                               \
    __shared__ unsigned short b_sh[128*64];                                               \
    const int tid = threadIdx.x, lane = tid & 63, wave = tid >> 6;                        \
    const int bm = blockIdx.y * 128, bn = blockIdx.x * 128;                               \
    const int wr = (wave >> 1) * 64, wc = (wave & 1) * 64;                                \
    const int l16 = lane & 15, q4 = lane >> 4;                                            \
    const int grow8 = lane >> 3;                                                          \
    const int gsl = ((lane & 7) ^ grow8) * 8;                                             \
    f32x4 acc[4][4] = {};                                                                 \
    for (int k0 = 0; k0 < EE; k0 += 64) {                                                 \
        _Pragma("unroll")                                                                 \
        for (int i = 0; i < 4; ++i) {                                                     \
            const int ch = wave * 4 + i;                                                  \
            load_lds16(&A_[(size_t)(bm + ch*8 + grow8)*EE + k0 + gsl], a_sh + ch*512);    \
            load_lds16(&W_[(size_t)(bn + ch*8 + grow8)*EE + k0 + gsl], b_sh + ch*512);    \
        }                                                                                 \
        __syncthreads();                                                                  \
        _Pragma("unroll")                                                                 \
        for (int kh = 0; kh < 2; ++kh) {                                                  \
            short8v af[4], bf[4];                                                         \
            _Pragma("unroll")                                                             \
            for (int mi = 0; mi < 4; ++mi)                                                \
                af[mi] = *(const short8v*)((const char*)a_sh                              \
                           + (size_t)(wr + mi*16 + l16)*128 + (((kh*4 + q4) ^ (l16 & 7))*16)); \
            _Pragma("unroll")                                                             \
            for (int ni = 0; ni < 4; ++ni)                                                \
                bf[ni] = *(const short8v*)((const char*)b_sh                              \
                           + (size_t)(wc + ni*16 + l16)*128 + (((kh*4 + q4) ^ (l16 & 7))*16)); \
            _Pragma("unroll")                                                             \
            for (int mi = 0; mi < 4; ++mi)                                                \
                _Pragma("unroll")                                                         \
                for (int ni = 0; ni < 4; ++ni)                                            \
                    acc[mi][ni] = __builtin_amdgcn_mfma_f32_16x16x32_bf16(af[mi], bf[ni], acc[mi][ni], 0, 0, 0); \
        }                                                                                 \
        __syncthreads();                                                                  \
    }

// QKV fused: W = [Wq;Wk;Wv] (3072 x 1024). Segment uniform per block.
__global__ __launch_bounds__(256) void gemm_qkv(const unsigned short* __restrict__ A,
                                                const unsigned short* __restrict__ W,
                                                const float* __restrict__ bq,
                                                const float* __restrict__ bk,
                                                const float* __restrict__ bv,
                                                unsigned short* __restrict__ qo,
                                                unsigned short* __restrict__ ko,
                                                unsigned short* __restrict__ vo) {
    GEMM128_BODY(A, W)
    const int seg = blockIdx.x >> 3;
    const float* bias = seg == 0 ? bq : (seg == 1 ? bk : bv);
    #pragma unroll
    for (int mi = 0; mi < 4; ++mi) {
        #pragma unroll
        for (int ni = 0; ni < 4; ++ni) {
            #pragma unroll
            for (int r = 0; r < 4; ++r) {
                const int m  = bm + wr + mi*16 + (lane >> 4)*4 + r;
                const int nn = (bn & 1023) + wc + ni*16 + l16;
                const float v = acc[mi][ni][r] + bias[nn];
                const int l = m >> 3, b = m & 7, h = nn >> 6, d = nn & 63;
                // Q pre-scaled by SCALE*log2e so attention softmax runs in exp2 domain
                if (seg == 0)      qo[((size_t)(b*HH + h) * LL + l) * HD + d] = tobf(v * (0.125f * LOG2E));
                else if (seg == 1) ko[((size_t)(b*HH + h) * LL + l) * HD + d] = tobf(v);
                else               vo[((size_t)(b*HH + h) * HD + d) * LL + l] = tobf(v); // V^T
            }
        }
    }
}

// Output projection + bias + residual, f32 out.
__global__ __launch_bounds__(256) void gemm_o(const unsigned short* __restrict__ A,
                                              const unsigned short* __restrict__ W,
                                              const float* __restrict__ bias,
                                              const float* __restrict__ xres,
                                              float* __restrict__ outf) {
    GEMM128_BODY(A, W)
    #pragma unroll
    for (int mi = 0; mi < 4; ++mi) {
        #pragma unroll
        for (int ni = 0; ni < 4; ++ni) {
            #pragma unroll
            for (int r = 0; r < 4; ++r) {
                const int m = bm + wr + mi*16 + (lane >> 4)*4 + r;
                const int n = bn + wc + ni*16 + l16;
                outf[(size_t)m * EE + n] = acc[mi][ni][r] + bias[n] + xres[(size_t)m * EE + n];
            }
        }
    }
}

// ---------------- Flash attention, m214 structure ----------------------------
// 4 waves/block, 32 q/wave (q = lane&31), KV tile 64, swapped QK^T with
// mfma_f32_32x32x16_bf16: S^T[k][q], k lane-local -> in-register softmax
// (log2 domain: Q pre-scaled by SCALE*log2e, mask folded via fmaf*log2e, exp2f).
// Mask register-double-buffered (issued one substep ahead). Tree reductions.
// K & V^T double-buffered LDS via pre-swizzled global_load_lds (T2/T14/rule 21).
__global__ __launch_bounds__(256) void attn_kernel(const unsigned short* __restrict__ qarr,
                                                   const unsigned short* __restrict__ karr,
                                                   const unsigned short* __restrict__ vtarr,
                                                   const float* __restrict__ mask,
                                                   unsigned short* __restrict__ attn_out) {
    __shared__ __attribute__((aligned(16))) unsigned short k_sh[2][64*64];  // [kv64][d64]
    __shared__ __attribute__((aligned(16))) unsigned short v_sh[2][64*64];  // [d64][kv64]
    const int tid = threadIdx.x, lane = tid & 63, wave = tid >> 6;
    const int l32 = lane & 31, hi = lane >> 5;
    const int bh = blockIdx.y;
    const int qtok = blockIdx.x * 128 + wave * 32 + l32;
    const unsigned short* qb = qarr  + (size_t)bh * LL * HD;
    const unsigned short* kb = karr  + (size_t)bh * LL * HD;
    const unsigned short* vb = vtarr + (size_t)bh * HD * LL;

    // Q B-frag: col q=l32, k-rows d = dc*16 + hi*8 + {0..7}
    short8v qf[4];
    #pragma unroll
    for (int dc = 0; dc < 4; ++dc)
        qf[dc] = *(const short8v*)&qb[(size_t)qtok * HD + dc*16 + hi*8];

    f32x16 acc[2] = {};           // O^T accumulator: dtile 0 (d 0..31), 1 (d 32..63)
    float mrun = -1e30f, srun = 0.f;

    // stage tile (64 keys) via global_load_lds; source chunk pre-swizzled so
    // LDS[row][slot] = global chunk (slot ^ (row&7))  [rule #21 involution]
    auto stage = [&](int buf, int kv) {
        #pragma unroll
        for (int i = 0; i < 2; ++i) {
            const int r = wave*16 + i*8 + (lane >> 3);
            const int c = ((lane & 7) ^ (r & 7)) * 8;
            load_lds16(&kb[(size_t)(kv + r) * HD + c], &k_sh[buf][(wave*16 + i*8) * 64]);
            load_lds16(&vb[(size_t)r * LL + kv + c],   &v_sh[buf][(wave*16 + i*8) * 64]);
        }
    };

    const float* mbase = &mask[(size_t)qtok * LL + hi*4];
    float4 mcur[4], mnxt[4];
    #pragma unroll
    for (int g = 0; g < 4; ++g) mcur[g] = *(const float4*)&mbase[g*8];   // (t=0,sub=0)

    stage(0, 0);
    for (int t = 0; t < LL/64; ++t) {
        const int buf = t & 1;
        __syncthreads();                       // compiler emits vmcnt(0) drain
        if (t < LL/64 - 1) stage(buf ^ 1, (t + 1) * 64);

        #pragma unroll
        for (int sub = 0; sub < 2; ++sub) {
            // ---- prefetch next substep's mask (used one substep later) ----
            {
                const int nt = (sub == 0) ? t : (t < LL/64 - 1 ? t + 1 : t);
                const int ns = sub ^ 1;
                const float* mrow = &mbase[(size_t)nt*64 + ns*32];
                #pragma unroll
                for (int g = 0; g < 4; ++g) mnxt[g] = *(const float4*)&mrow[g*8];
            }
            // ---- S^T = K . Q^T over d=64 (4 chained mfma) ----
            f32x16 s = {};
            __builtin_amdgcn_s_setprio(1);
            #pragma unroll
            for (int dc = 0; dc < 4; ++dc) {
                const int row = sub*32 + l32;
                const short8v kf = *(const short8v*)((const char*)&k_sh[buf][0]
                                     + (size_t)row*128 + (((dc*2 + hi) ^ (l32 & 7)) * 16));
                s = __builtin_amdgcn_mfma_f32_32x32x16_bf16(kf, qf[dc], s, 0, 0, 0);
            }
            __builtin_amdgcn_s_setprio(0);
            // ---- + mask*log2e (registers, prefetched last substep) ----
            #pragma unroll
            for (int g = 0; g < 4; ++g) {
                s[4*g+0] = fmaf(mcur[g].x, LOG2E, s[4*g+0]);
                s[4*g+1] = fmaf(mcur[g].y, LOG2E, s[4*g+1]);
                s[4*g+2] = fmaf(mcur[g].z, LOG2E, s[4*g+2]);
                s[4*g+3] = fmaf(mcur[g].w, LOG2E, s[4*g+3]);
            }
            #pragma unroll
            for (int g = 0; g < 4; ++g) mcur[g] = mnxt[g];
            // ---- in-register softmax, log2 domain (q column lane-local) ----
            const float a0 = max3f(s[0],  s[1],  s[2]);
            const float a1 = max3f(s[3],  s[4],  s[5]);
            const float a2 = max3f(s[6],  s[7],  s[8]);
            const float a3 = max3f(s[9],  s[10], s[11]);
            const float a4 = max3f(s[12], s[13], s[14]);
            float pm = fmaxf(max3f(a0, a1, a2), max3f(a3, a4, s[15]));
            pm = fmaxf(pm, __shfl_xor(pm, 32));
            if (__any(pm - mrun > 8.0f)) {     // T13 defer-max rescale
                const float mn = fmaxf(mrun, pm);
                const float al = exp2f(mrun - mn);
                #pragma unroll
                for (int i = 0; i < 16; ++i) { acc[0][i] *= al; acc[1][i] *= al; }
                srun *= al;
                mrun = mn;
            }
            float p[16];
            #pragma unroll
            for (int i = 0; i < 16; ++i) p[i] = exp2f(s[i] - mrun);
            // pairwise sum tree (depth 4)
            const float t0 = p[0]+p[1],   t1 = p[2]+p[3],   t2 = p[4]+p[5],   t3 = p[6]+p[7];
            const float t4 = p[8]+p[9],   t5 = p[10]+p[11], t6 = p[12]+p[13], t7 = p[14]+p[15];
            const float u0 = t0+t1, u1 = t2+t3, u2 = t4+t5, u3 = t6+t7;
            float rs = (u0+u1) + (u2+u3);
            rs += __shfl_xor(rs, 32);
            srun += rs;
            // ---- P -> bf16 B-frags via cvt_pk + permlane32_swap (T12) ----
            unsigned w[8];
            #pragma unroll
            for (int j = 0; j < 8; ++j)
                asm("v_cvt_pk_bf16_f32 %0, %1, %2" : "=v"(w[j]) : "v"(p[2*j]), "v"(p[2*j+1]));
            asm volatile("v_permlane32_swap_b32 %0, %1" : "+v"(w[0]), "+v"(w[2]));
            asm volatile("v_permlane32_swap_b32 %0, %1" : "+v"(w[1]), "+v"(w[3]));
            asm volatile("v_permlane32_swap_b32 %0, %1" : "+v"(w[4]), "+v"(w[6]));
            asm volatile("v_permlane32_swap_b32 %0, %1" : "+v"(w[5]), "+v"(w[7]));
            union { uint4 u; short8v s8; } pb0, pb1;
            pb0.u = make_uint4(w[0], w[1], w[2], w[3]);   // k-chain 0..15
            pb1.u = make_uint4(w[4], w[5], w[6], w[7]);   // k-chain 16..31
            // ---- O^T += V^T . P  (4 mfma) ----
            __builtin_amdgcn_s_setprio(1);
            #pragma unroll
            for (int dt = 0; dt < 2; ++dt) {
                const int row = dt*32 + l32;
                const short8v vf0 = *(const short8v*)((const char*)&v_sh[buf][0]
                                      + (size_t)row*128 + ((((sub*2+0)*2 + hi) ^ (l32 & 7)) * 16));
                const short8v vf1 = *(const short8v*)((const char*)&v_sh[buf][0]
                                      + (size_t)row*128 + ((((sub*2+1)*2 + hi) ^ (l32 & 7)) * 16));
                acc[dt] = __builtin_amdgcn_mfma_f32_32x32x16_bf16(vf0, pb0.s8, acc[dt], 0, 0, 0);
                acc[dt] = __builtin_amdgcn_mfma_f32_32x32x16_bf16(vf1, pb1.s8, acc[dt], 0, 0, 0);
            }
            __builtin_amdgcn_s_setprio(0);
        }
    }
    // ---- epilogue: O = acc/srun, packed 8B stores ----
    const float inv = 1.0f / srun;
    const int b = bh >> 4, h = bh & 15;
    unsigned short* orow = attn_out + ((size_t)qtok * BB + b) * EE + h * HD;
    #pragma unroll
    for (int dt = 0; dt < 2; ++dt) {
        #pragma unroll
        for (int g = 0; g < 4; ++g) {
            const float a0 = acc[dt][4*g+0]*inv, a1 = acc[dt][4*g+1]*inv;
            const float a2 = acc[dt][4*g+2]*inv, a3 = acc[dt][4*g+3]*inv;
            unsigned lo, hw;
            asm("v_cvt_pk_bf16_f32 %0, %1, %2" : "=v"(lo) : "v"(a0), "v"(a1));
            asm("v_cvt_pk_bf16_f32 %0, %1, %2" : "=v"(hw) : "v"(a2), "v"(a3));
            *(uint2*)&orow[dt*32 + g*8 + hi*4] = make_uint2(lo, hw);
        }
    }
}

extern "C" void kernel_launch(void* const* d_in, const int* in_sizes, int n_in,
                              void* d_out, int out_size, void* d_ws, size_t ws_size,
                              hipStream_t stream) {
    (void)in_sizes; (void)n_in; (void)out_size; (void)ws_size;
    const float* x     = (const float*)d_in[0];
    const float* mask  = (const float*)d_in[1];
    const float* Wq    = (const float*)d_in[2];
    const float* bq    = (const float*)d_in[3];
    const float* Wk    = (const float*)d_in[4];
    const float* bk    = (const float*)d_in[5];
    const float* Wv    = (const float*)d_in[6];
    const float* bv    = (const float*)d_in[7];
    const float* Wo    = (const float*)d_in[8];
    const float* bo    = (const float*)d_in[9];
    const float* gamma = (const float*)d_in[10];
    const float* beta  = (const float*)d_in[11];
    float* out = (float*)d_out;

    // workspace layout (ushort units)
    unsigned short* ws   = (unsigned short*)d_ws;
    unsigned short* ln   = ws;                          // 8192*1024 (reused as attnb)
    unsigned short* wqkv = ln   + (size_t)MROWS * EE;   // 3 x 1024 x 1024 (Wq;Wk;Wv)
    unsigned short* wob  = wqkv + (size_t)3 * EE * EE;
    unsigned short* qb   = wob  + (size_t)EE * EE;      // (B,H,L,HD)
    unsigned short* kbp  = qb   + (size_t)BB * HH * LL * HD;
    unsigned short* vtb  = kbp  + (size_t)BB * HH * LL * HD;  // (B,H,HD,L)
    unsigned short* attnb = ln;                         // reuse after QKV GEMM

    convw4_kernel<<<dim3(1024, 4), 256, 0, stream>>>(
        Wq, Wk, Wv, Wo,
        wqkv, wqkv + (size_t)EE * EE, wqkv + (size_t)2 * EE * EE, wob);
    ln_kernel<<<MROWS, 256, 0, stream>>>(x, gamma, beta, ln);

    gemm_qkv<<<dim3(24, 64), 256, 0, stream>>>(ln, wqkv, bq, bk, bv, qb, kbp, vtb);

    attn_kernel<<<dim3(LL / 128, BB * HH), 256, 0, stream>>>(qb, kbp, vtb, mask, attnb);

    gemm_o<<<dim3(8, 64), 256, 0, stream>>>(attnb, wob, bo, x, out);
}